// Round 8
// baseline (429.126 us; speedup 1.0000x reference)
//
#include <hip/hip_runtime.h>
#include <hip/hip_fp16.h>

// B=4, T=2048, C=1024. Single-head causal attention, fp32 in/out.
// Internals fp16 (MFMA f32_16x16x32_f16), fp32 accum + fp32 softmax math.
// R16: R15's scores+pv merge, but with a GRAPH-SAFE software global
// barrier instead of hipLaunchCooperativeKernel (which is not capturable
// into a HIP graph -> R15's kernel never ran, out stayed zero, absmax ==
// max|ref| = 3.4). Mechanism per G16: device-scope atomics + fences.
//  - __launch_bounds__(256,3): 3 blocks/CU guaranteed -> capacity 768 >=
//    544 blocks all co-resident -> spin barrier cannot deadlock.
//  - arrive: syncthreads; threadfence (release S/rsum); lane0
//    atomicAdd(bar)+spin acquire-load until 544; syncthreads; threadfence
//    (acquire — invalidate stale S lines from the previous graph replay).
//  - bar = rsum[8192], zeroed by convert_k (kernel-boundary visibility).
// Phase bodies byte-identical to R14/R15 (proven): dense-triangular
// XCD-swizzled scores writing E=exp(x*scale-6) + atomic rsum; pv 128x128
// d-fastest longest-first, divide by rsum. qkv (68us, 758 TF) frozen.

typedef __attribute__((ext_vector_type(8))) _Float16 half8;
typedef __attribute__((ext_vector_type(4))) _Float16 half4;
typedef __attribute__((ext_vector_type(4))) float f32x4;

// ---------------------------------------------------------------------------
// NT-GEMM core (scores / pv), reg-staged prefetch. TM x TN tile, BK=64,
// 256 thr = WM*WN waves. LDS swizzle verified 0 conflicts.
// ---------------------------------------------------------------------------
template<int TM, int TN, int WM, int WN, bool SWAP>
__device__ __forceinline__ void gemm_nt_core(
    const _Float16* __restrict__ A, const _Float16* __restrict__ B,
    int lda, int ldb, int k0, int k1,
    _Float16* ldsA, _Float16* ldsB,      // TM*64, TN*64 halves
    f32x4 acc[TM / (WM * 16)][TN / (WN * 16)])
{
    constexpr int FM = TM / (WM * 16), FN = TN / (WN * 16);
    constexpr int NA = TM / 32, NB = TN / 32;   // 16B chunks per thread
    const int t    = threadIdx.x;
    const int lane = t & 63;
    const int w    = t >> 6;
    const int wm   = w % WM;
    const int wn   = w / WM;
    const int lr   = lane & 15;
    const int lq   = lane >> 4;

    const _Float16* ga[NA]; int loA[NA];
    const _Float16* gb[NB]; int loB[NB];
#pragma unroll
    for (int i = 0; i < NA; ++i) {
        int f = t + 256 * i;
        int r = f >> 3, c = (f & 7) ^ ((f >> 3) & 7);
        ga[i] = A + (size_t)r * lda + c * 8;
        loA[i] = f * 8;
    }
#pragma unroll
    for (int i = 0; i < NB; ++i) {
        int f = t + 256 * i;
        int r = f >> 3, c = (f & 7) ^ ((f >> 3) & 7);
        gb[i] = B + (size_t)r * ldb + c * 8;
        loB[i] = f * 8;
    }

    int offA[2][FM], offB[2][FN];
#pragma unroll
    for (int h = 0; h < 2; ++h) {
#pragma unroll
        for (int i = 0; i < FM; ++i) {
            int R = wm * (TM / WM) + i * 16 + lr;
            offA[h][i] = (8 * R + ((h * 4 + lq) ^ (R & 7))) * 8;
        }
#pragma unroll
        for (int i = 0; i < FN; ++i) {
            int R = wn * (TN / WN) + i * 16 + lr;
            offB[h][i] = (8 * R + ((h * 4 + lq) ^ (R & 7))) * 8;
        }
    }

    // prologue: tile k0 -> registers
    half8 va[NA], vb[NB];
#pragma unroll
    for (int i = 0; i < NA; ++i) va[i] = *(const half8*)(ga[i] + k0);
#pragma unroll
    for (int i = 0; i < NB; ++i) vb[i] = *(const half8*)(gb[i] + k0);

    for (int k = k0; k < k1; k += 64) {
        __syncthreads();               // prev iter's LDS readers done
#pragma unroll
        for (int i = 0; i < NA; ++i) *(half8*)(ldsA + loA[i]) = va[i];
#pragma unroll
        for (int i = 0; i < NB; ++i) *(half8*)(ldsB + loB[i]) = vb[i];
        if (k + 64 < k1) {             // issue next tile's loads; they fly
#pragma unroll                         // during this iter's compute phase
            for (int i = 0; i < NA; ++i) va[i] = *(const half8*)(ga[i] + k + 64);
#pragma unroll
            for (int i = 0; i < NB; ++i) vb[i] = *(const half8*)(gb[i] + k + 64);
        }
        __syncthreads();               // LDS writes visible

#pragma unroll
        for (int h = 0; h < 2; ++h) {
            half8 af[FM], bf[FN];
#pragma unroll
            for (int i = 0; i < FM; ++i) af[i] = *(const half8*)(ldsA + offA[h][i]);
#pragma unroll
            for (int i = 0; i < FN; ++i) bf[i] = *(const half8*)(ldsB + offB[h][i]);
#pragma unroll
            for (int mi = 0; mi < FM; ++mi)
#pragma unroll
                for (int ni = 0; ni < FN; ++ni) {
                    if constexpr (SWAP)
                        acc[mi][ni] = __builtin_amdgcn_mfma_f32_16x16x32_f16(
                            bf[ni], af[mi], acc[mi][ni], 0, 0, 0);
                    else
                        acc[mi][ni] = __builtin_amdgcn_mfma_f32_16x16x32_f16(
                            af[mi], bf[ni], acc[mi][ni], 0, 0, 0);
                }
        }
    }
}

// ---------------------------------------------------------------------------
// 256x128 counted-vmcnt core (qkv) — unchanged from R10 (proven).
// ---------------------------------------------------------------------------
__device__ __forceinline__ void gload_lds16(const void* g, void* l)
{
    __builtin_amdgcn_global_load_lds(
        (const __attribute__((address_space(1))) void*)g,
        (__attribute__((address_space(3))) void*)l, 16, 0, 0);
}

template<bool SWAP>
__device__ __forceinline__ void gemm_nt_256x128(
    const _Float16* __restrict__ A, const _Float16* __restrict__ B,
    const int lda, const int ldb, const int kTiles,   // kTiles even, >= 4
    _Float16* lds, f32x4 acc[4][4])
{
    const int t    = threadIdx.x;
    const int lane = t & 63;
    const int w    = t >> 6;
    const int wm   = w & 3;          // M quarter (64 rows)
    const int wn   = w >> 2;         // N half (64 cols)
    const int lr   = lane & 15;
    const int lq   = lane >> 4;

    const int r0 = t >> 3;                       // 0..63 within a slot
    const int c0 = (t & 7) ^ (r0 & 7);
    const _Float16* gA = A + (size_t)r0 * lda + c0 * 8;
    const _Float16* gB = B + (size_t)r0 * ldb + c0 * 8;

    char* ldsc = (char*)lds;
    char* stA = ldsc + w * 1024;              // + BUF*32768 + slot*8192
    char* stB = ldsc + 65536 + w * 1024;      // + BUF*16384 + slot*8192

    const int x0 = ((0 + lq) ^ (lr & 7)) * 16;
    const int x1 = ((4 + lq) ^ (lr & 7)) * 16;
    const char* rdA = ldsc + wm * 8192 + lr * 128;           // + BUF*32768 + mi*2048
    const char* rdB = ldsc + 65536 + wn * 8192 + lr * 128;   // + BUF*16384 + ni*2048

    half8 af[4][2], bf01[2][2], bf23[2][2];

#define STGA1(BUF, S, KOFF)                                                   \
    gload_lds16(gA + (size_t)(S) * 64 * lda + (KOFF),                         \
                stA + (BUF) * 32768 + (S) * 8192)

#define STGB1(BUF, S, KOFF)                                                   \
    gload_lds16(gB + (size_t)(S) * 64 * ldb + (KOFF),                         \
                stB + (BUF) * 16384 + (S) * 8192)

#define LDA_ALL(BUF) do {                                                     \
    const char* _p = rdA + (BUF) * 32768;                                     \
    _Pragma("unroll")                                                         \
    for (int mi = 0; mi < 4; ++mi) {                                          \
        af[mi][0] = *(const half8*)(_p + mi * 2048 + x0);                     \
        af[mi][1] = *(const half8*)(_p + mi * 2048 + x1);                     \
    }                                                                         \
} while (0)

#define LDB_H(DST, BUF, NQ) do {                                              \
    const char* _p = rdB + (BUF) * 16384 + (NQ) * 4096;                       \
    _Pragma("unroll")                                                         \
    for (int ni = 0; ni < 2; ++ni) {                                          \
        DST[ni][0] = *(const half8*)(_p + ni * 2048 + x0);                    \
        DST[ni][1] = *(const half8*)(_p + ni * 2048 + x1);                    \
    }                                                                         \
} while (0)

#define MFMA_NH(NQ, BSRC) do {                                                \
    _Pragma("unroll")                                                         \
    for (int mi = 0; mi < 4; ++mi)                                            \
    _Pragma("unroll")                                                         \
    for (int ni = 0; ni < 2; ++ni)                                            \
    _Pragma("unroll")                                                         \
    for (int kh = 0; kh < 2; ++kh) {                                          \
        if constexpr (SWAP)                                                   \
            acc[mi][(NQ)*2+ni] = __builtin_amdgcn_mfma_f32_16x16x32_f16(      \
                BSRC[ni][kh], af[mi][kh], acc[mi][(NQ)*2+ni], 0, 0, 0);       \
        else                                                                  \
            acc[mi][(NQ)*2+ni] = __builtin_amdgcn_mfma_f32_16x16x32_f16(      \
                af[mi][kh], BSRC[ni][kh], acc[mi][(NQ)*2+ni], 0, 0, 0);       \
    }                                                                         \
} while (0)

#define PH_PRE() do {                                                         \
    asm volatile("" ::: "memory");                                            \
    __builtin_amdgcn_s_barrier();                                             \
    asm volatile("s_waitcnt lgkmcnt(0)" ::: "memory");                        \
    __builtin_amdgcn_sched_barrier(0);                                        \
    __builtin_amdgcn_s_setprio(1);                                            \
} while (0)

#define PH_POST() do {                                                        \
    __builtin_amdgcn_s_setprio(0);                                            \
    __builtin_amdgcn_sched_barrier(0);                                        \
    __builtin_amdgcn_s_barrier();                                             \
    asm volatile("" ::: "memory");                                            \
} while (0)

#define KTILE(KT, BUF) do {                                                   \
    const int _k1 = ((KT) + 1) * 64, _k2 = ((KT) + 2) * 64;                   \
    const bool _s1 = (KT) + 1 < kTiles, _s2 = (KT) + 2 < kTiles;              \
    /* ph1 */                                                                 \
    LDA_ALL(BUF);                                                             \
    LDB_H(bf01, BUF, 0);                                                      \
    if (_s1) { STGB1((BUF) ^ 1, 0, _k1); STGB1((BUF) ^ 1, 1, _k1); }          \
    PH_PRE(); MFMA_NH(0, bf01); PH_POST();                                    \
    /* ph2 */                                                                 \
    LDB_H(bf23, BUF, 1);                                                      \
    if (_s2) { STGA1(BUF, 0, _k2); STGA1(BUF, 1, _k2);                        \
               STGA1(BUF, 2, _k2); STGA1(BUF, 3, _k2); }                      \
    asm volatile("" ::: "memory");                                            \
    __builtin_amdgcn_s_barrier();                                             \
    asm volatile("s_waitcnt lgkmcnt(0)" ::: "memory");                        \
    __builtin_amdgcn_sched_barrier(0);                                        \
    __builtin_amdgcn_s_setprio(1);                                            \
    MFMA_NH(1, bf23);                                                         \
    __builtin_amdgcn_s_setprio(0);                                            \
    if (_s2) asm volatile("s_waitcnt vmcnt(4)" ::: "memory");                 \
    else     asm volatile("s_waitcnt vmcnt(0)" ::: "memory");                 \
    __builtin_amdgcn_sched_barrier(0);                                        \
    __builtin_amdgcn_s_barrier();                                             \
    asm volatile("" ::: "memory");                                            \
} while (0)

    // prologue: tile0 fully (6 loads), then tile1's A (4 loads);
    // vmcnt(4) drains tile0, keeps tile1's A in flight.
    STGA1(0, 0, 0); STGA1(0, 1, 0); STGA1(0, 2, 0); STGA1(0, 3, 0);
    STGB1(0, 0, 0); STGB1(0, 1, 0);
    if (kTiles > 1) { STGA1(1, 0, 64); STGA1(1, 1, 64);
                      STGA1(1, 2, 64); STGA1(1, 3, 64); }
    if (kTiles > 1) asm volatile("s_waitcnt vmcnt(4)" ::: "memory");
    else            asm volatile("s_waitcnt vmcnt(0)" ::: "memory");
    __builtin_amdgcn_sched_barrier(0);
    __builtin_amdgcn_s_barrier();
    asm volatile("" ::: "memory");

#pragma unroll 1
    for (int kt = 0; kt < kTiles; kt += 2) {
        KTILE(kt, 0);
        KTILE(kt + 1, 1);
    }

#undef STGA1
#undef STGB1
#undef LDA_ALL
#undef LDB_H
#undef MFMA_NH
#undef PH_PRE
#undef PH_POST
#undef KTILE
}

// ---------------------------------------------------------------------------
// Merged f32->f16 conversion: x (8M elems) then Wq|Wk|Wv (3x1M) -> Wh.
// Also zeroes rsum[8192] and the barrier counter at rsum[8192].
// ---------------------------------------------------------------------------
__global__ __launch_bounds__(256) void convert_k(
    const float* __restrict__ x, const float* __restrict__ Wq,
    const float* __restrict__ Wk, const float* __restrict__ Wv,
    _Float16* __restrict__ xh, _Float16* __restrict__ Wh,
    float* __restrict__ rsum)
{
    int g = blockIdx.x * 256 + threadIdx.x;
    if (g < 2048) {
        f32x4 z = { 0.f, 0.f, 0.f, 0.f };
        *(f32x4*)(rsum + g * 4) = z;
    }
    if (g == 2048) *(unsigned*)(rsum + 8192) = 0u;   // sw-barrier counter
    int i = g * 4;
    const float* src;
    _Float16* dst;
    if (i < 8388608) {                       // 4*2048*1024
        src = x + i; dst = xh + i;
    } else {
        int j = i - 8388608;                 // 0 .. 3*1048576
        int wsel = j >> 20;                  // each W is 2^20 elements
        int off  = j & 1048575;
        src = (wsel == 0 ? Wq : wsel == 1 ? Wk : Wv) + off;
        dst = Wh + j;
    }
    float4 f = *(const float4*)src;
    half4 h = { (_Float16)f.x, (_Float16)f.y, (_Float16)f.z, (_Float16)f.w };
    *(half4*)dst = h;
}

// ---------------------------------------------------------------------------
// Fused QKV on the 256x128 core: grid (32,8,3) = 768 blocks = 3.0 exact
// rounds on 256 CUs. z=0 Q[t][d], z=1 K[s][d] (SWAP, half4 along d);
// z=2 Vt[b][d][t] (non-SWAP, half4 along t).
// ---------------------------------------------------------------------------
__global__ __launch_bounds__(512, 2) void qkv_gemm256_k(
    const _Float16* __restrict__ xh, const _Float16* __restrict__ Wh,
    _Float16* __restrict__ Q, _Float16* __restrict__ K,
    _Float16* __restrict__ Vt)
{
    __shared__ __align__(16) _Float16 lds[49152];   // 96 KiB
    const int tileM = blockIdx.x * 256;
    const int tileN = blockIdx.y * 128;
    const int z     = blockIdx.z;
    const _Float16* W = Wh + (size_t)z * 1024 * 1024;

    const int lane = threadIdx.x & 63;
    const int w    = threadIdx.x >> 6;
    const int wm = w & 3, wn = w >> 2;
    const int lr = lane & 15, lq = lane >> 4;

    f32x4 acc[4][4] = {};
    if (z == 2) {
        gemm_nt_256x128<false>(xh + (size_t)tileM * 1024,
                               W + (size_t)tileN * 1024,
                               1024, 1024, 16, lds, acc);
#pragma unroll
        for (int mi = 0; mi < 4; ++mi)
#pragma unroll
            for (int ni = 0; ni < 4; ++ni) {
                int m0 = tileM + wm * 64 + mi * 16 + lq * 4;
                int n  = tileN + wn * 64 + ni * 16 + lr;
                int b = m0 >> 11, tt = m0 & 2047;
                half4 h = { (_Float16)acc[mi][ni][0], (_Float16)acc[mi][ni][1],
                            (_Float16)acc[mi][ni][2], (_Float16)acc[mi][ni][3] };
                *(half4*)(Vt + (size_t)b * 2048 * 1024 + (size_t)n * 2048 + tt) = h;
            }
    } else {
        gemm_nt_256x128<true>(xh + (size_t)tileM * 1024,
                              W + (size_t)tileN * 1024,
                              1024, 1024, 16, lds, acc);
        _Float16* O = (z == 0) ? Q : K;
#pragma unroll
        for (int mi = 0; mi < 4; ++mi)
#pragma unroll
            for (int ni = 0; ni < 4; ++ni) {
                int tt = tileM + wm * 64 + mi * 16 + lr;
                int d0 = tileN + wn * 64 + ni * 16 + lq * 4;
                half4 h = { (_Float16)acc[mi][ni][0], (_Float16)acc[mi][ni][1],
                            (_Float16)acc[mi][ni][2], (_Float16)acc[mi][ni][3] };
                *(half4*)(O + (size_t)tt * 1024 + d0) = h;
            }
    }
}

// ---------------------------------------------------------------------------
// MERGED scores+pv kernel, 544 blocks x 256 thr, software global barrier.
// __launch_bounds__(256,3): >=3 blocks/CU -> capacity 768 >= 544, all
// blocks co-resident -> spin barrier deadlock-free.
// Phase 1 (all blocks): dense triangular scores, XCD chunk swizzle
// (544=68x8), E = exp(x*scale-6) (masked -> 0; constant-shift softmax,
// verified R12-R14), atomic row-sums into rsum.
// Barrier: threadfence (release) -> lane0 atomicAdd+spin (agent scope) ->
// threadfence (acquire; invalidates stale S/rsum lines from prev replay).
// Phase 2 (blocks 0..511): pv 128x128, d-fastest decode (8 adjacent blocks
// share one P row-panel), longest-ti-first; divide by rsum in epilogue.
// ---------------------------------------------------------------------------
__global__ __launch_bounds__(256, 3) void attn_sp_k(
    const _Float16* __restrict__ Q, const _Float16* __restrict__ K,
    _Float16* S, const _Float16* __restrict__ Vt,
    float* rsum, unsigned* bar, float* __restrict__ out)
{
    __shared__ __align__(16) _Float16 ldsA[128 * 64];
    __shared__ __align__(16) _Float16 ldsB[128 * 64];

    const int lane = threadIdx.x & 63;
    const int w    = threadIdx.x >> 6;
    const int wm = w & 1, wn = w >> 1;
    const int lr = lane & 15, lq = lane >> 4;

    // ---------------- phase 1: scores ----------------
    {
        const int bid = blockIdx.x;
        const int n   = (bid & 7) * 68 + (bid >> 3);   // bijective XCD swizzle
        const int b   = n / 136;
        const int m   = n - b * 136;
        int ti = (int)((sqrtf(8.f * (float)m + 1.f) - 1.f) * 0.5f);
        while ((ti + 1) * (ti + 2) / 2 <= m) ++ti;     // fixup (float safety)
        while (ti * (ti + 1) / 2 > m) --ti;
        const int si = m - ti * (ti + 1) / 2;
        const int tileT = ti * 128, tileS = si * 128;

        f32x4 acc[4][4] = {};
        gemm_nt_core<128, 128, 2, 2, true>(
            Q + (size_t)b * 2048 * 1024 + (size_t)tileT * 1024,
            K + (size_t)b * 2048 * 1024 + (size_t)tileS * 1024,
            1024, 1024, 0, 1024, ldsA, ldsB, acc);

        const float scale = 0.03125f;  // 1024^-0.5
        float rp[4] = { 0.f, 0.f, 0.f, 0.f };
#pragma unroll
        for (int mi = 0; mi < 4; ++mi)
#pragma unroll
            for (int ni = 0; ni < 4; ++ni) {
                int tt = tileT + wm * 64 + mi * 16 + lr;
                int s0 = tileS + wn * 64 + ni * 16 + lq * 4;
                half4 h;
#pragma unroll
                for (int r = 0; r < 4; ++r) {
                    float e = __expf(fmaf(acc[mi][ni][r], scale, -6.0f));
                    h[r] = (s0 + r <= tt) ? (_Float16)e : (_Float16)0.f;
                    rp[mi] += (float)h[r];
                }
                *(half4*)(S + ((size_t)b * 2048 + tt) * 2048 + s0) = h;
            }

#pragma unroll
        for (int mi = 0; mi < 4; ++mi) {
            rp[mi] += __shfl_xor(rp[mi], 16);
            rp[mi] += __shfl_xor(rp[mi], 32);
        }
        if (lq == 0) {
#pragma unroll
            for (int mi = 0; mi < 4; ++mi) {
                int tt = tileT + wm * 64 + mi * 16 + lr;
                atomicAdd(&rsum[(size_t)b * 2048 + tt], rp[mi]);
            }
        }
    }

    // ---------------- software global barrier ----------------
    __syncthreads();                       // all block stores issued
    __threadfence();                       // release S + rsum device-wide
    if (threadIdx.x == 0) {
        __hip_atomic_fetch_add(bar, 1u, __ATOMIC_ACQ_REL,
                               __HIP_MEMORY_SCOPE_AGENT);
        unsigned v;
        do {
            v = __hip_atomic_load(bar, __ATOMIC_ACQUIRE,
                                  __HIP_MEMORY_SCOPE_AGENT);
        } while (v < 544u);
    }
    __syncthreads();
    __threadfence();                       // acquire side for S/rsum reads

    // ---------------- phase 2: pv ----------------
    if (blockIdx.x < 512) {
        const int n2 = blockIdx.x;
        const int d  = n2 & 7;                 // fastest: share P-panel
        const int tio = (n2 >> 3) & 15;
        const int b   = n2 >> 7;
        const int tileT = (15 - tio) * 128;    // longest-first
        const int tileD = d * 128;
        const int kEnd  = tileT + 128;

        f32x4 acc[4][4] = {};
        gemm_nt_core<128, 128, 2, 2, true>(
            S + ((size_t)b * 2048 + tileT) * 2048,
            Vt + (size_t)b * 1024 * 2048 + (size_t)tileD * 2048,
            2048, 2048, 0, kEnd, ldsA, ldsB, acc);

#pragma unroll
        for (int mi = 0; mi < 4; ++mi) {
            const int tt = tileT + wm * 64 + mi * 16 + lr;
            const float inv = 1.0f / rsum[(size_t)b * 2048 + tt];
#pragma unroll
            for (int ni = 0; ni < 4; ++ni) {
                int d0 = tileD + wn * 64 + ni * 16 + lq * 4;
                f32x4 o = { acc[mi][ni][0] * inv, acc[mi][ni][1] * inv,
                            acc[mi][ni][2] * inv, acc[mi][ni][3] * inv };
                *(f32x4*)(out + ((size_t)b * 2048 + tt) * 1024 + d0) = o;
            }
        }
    }
}

// ---------------------------------------------------------------------------
extern "C" void kernel_launch(void* const* d_in, const int* in_sizes, int n_in,
                              void* d_out, int out_size, void* d_ws, size_t ws_size,
                              hipStream_t stream)
{
    const float* x  = (const float*)d_in[0];
    const float* Wq = (const float*)d_in[1];
    const float* Wk = (const float*)d_in[2];
    const float* Wv = (const float*)d_in[3];
    float* out = (float*)d_out;

    char* ws = (char*)d_ws;
    // layout (MB): xh 0..16 | Wh 16..22 | Q 22..38 | K 38..54 | Vt 54..70 |
    // S16 70..102 | rsum 102..102.03 | bar.  Total ~102.1 MB.
    _Float16* xh = (_Float16*)(ws);
    _Float16* Wh = (_Float16*)(ws + (16u << 20));
    _Float16* Qh = (_Float16*)(ws + (22u << 20));
    _Float16* Kh = (_Float16*)(ws + (38u << 20));
    _Float16* Vt = (_Float16*)(ws + (54u << 20));
    _Float16* S  = (_Float16*)(ws + (70u << 20));
    float*    rs = (float*)   (ws + (102u << 20));
    unsigned* bar = (unsigned*)(rs + 8192);

    convert_k<<<11264, 256, 0, stream>>>(x, Wq, Wk, Wv, xh, Wh, rs);

    qkv_gemm256_k<<<dim3(32, 8, 3), 512, 0, stream>>>(xh, Wh, Qh, Kh, Vt);

    attn_sp_k<<<544, 256, 0, stream>>>(Qh, Kh, S, Vt, rs, bar, out);
}

// Round 9
// 321.148 us; speedup vs baseline: 1.3362x; 1.3362x over previous
//
#include <hip/hip_runtime.h>
#include <hip/hip_fp16.h>

// B=4, T=2048, C=1024. Single-head causal attention, fp32 in/out.
// Internals fp16 (MFMA f32_16x16x32_f16), fp32 accum + fp32 softmax math.
// R17: revert to R14 (235.4 us proven best; R15/R16 merge attempts failed:
// coop launch not graph-capturable, sw-barrier convoy = 281 us idle).
// Two targeted fixes on the cache-BW-bound scores/pv phase:
//  1. pv: 1-D grid 512 + bijective XCD chunk swizzle (n=(bid&7)*64+bid>>3)
//     -> each XCD owns 4 complete (b,d) Vt-panel groups (2 MB, fits its
//     4 MB L2). Vt was previously pulled into all 8 XCD L2s (16 sharing
//     blocks round-robined) = 8x L2-miss amplification on the largest
//     reuse term (~143 MB).
//  2. scores+pv: __launch_bounds__(256,4) (VGPR 84 measured in R16 -> 4
//     blocks/CU guaranteed, no spill) — more TLP to hide L2/L3 latency.
// qkv (68 us, 758 TF counted-vmcnt 256x128) and convert frozen.

typedef __attribute__((ext_vector_type(8))) _Float16 half8;
typedef __attribute__((ext_vector_type(4))) _Float16 half4;
typedef __attribute__((ext_vector_type(4))) float f32x4;

// ---------------------------------------------------------------------------
// NT-GEMM core (scores / pv), reg-staged prefetch. TM x TN tile, BK=64,
// 256 thr = WM*WN waves. LDS swizzle verified 0 conflicts.
// ---------------------------------------------------------------------------
template<int TM, int TN, int WM, int WN, bool SWAP>
__device__ __forceinline__ void gemm_nt_core(
    const _Float16* __restrict__ A, const _Float16* __restrict__ B,
    int lda, int ldb, int k0, int k1,
    _Float16* ldsA, _Float16* ldsB,      // TM*64, TN*64 halves
    f32x4 acc[TM / (WM * 16)][TN / (WN * 16)])
{
    constexpr int FM = TM / (WM * 16), FN = TN / (WN * 16);
    constexpr int NA = TM / 32, NB = TN / 32;   // 16B chunks per thread
    const int t    = threadIdx.x;
    const int lane = t & 63;
    const int w    = t >> 6;
    const int wm   = w % WM;
    const int wn   = w / WM;
    const int lr   = lane & 15;
    const int lq   = lane >> 4;

    const _Float16* ga[NA]; int loA[NA];
    const _Float16* gb[NB]; int loB[NB];
#pragma unroll
    for (int i = 0; i < NA; ++i) {
        int f = t + 256 * i;
        int r = f >> 3, c = (f & 7) ^ ((f >> 3) & 7);
        ga[i] = A + (size_t)r * lda + c * 8;
        loA[i] = f * 8;
    }
#pragma unroll
    for (int i = 0; i < NB; ++i) {
        int f = t + 256 * i;
        int r = f >> 3, c = (f & 7) ^ ((f >> 3) & 7);
        gb[i] = B + (size_t)r * ldb + c * 8;
        loB[i] = f * 8;
    }

    int offA[2][FM], offB[2][FN];
#pragma unroll
    for (int h = 0; h < 2; ++h) {
#pragma unroll
        for (int i = 0; i < FM; ++i) {
            int R = wm * (TM / WM) + i * 16 + lr;
            offA[h][i] = (8 * R + ((h * 4 + lq) ^ (R & 7))) * 8;
        }
#pragma unroll
        for (int i = 0; i < FN; ++i) {
            int R = wn * (TN / WN) + i * 16 + lr;
            offB[h][i] = (8 * R + ((h * 4 + lq) ^ (R & 7))) * 8;
        }
    }

    // prologue: tile k0 -> registers
    half8 va[NA], vb[NB];
#pragma unroll
    for (int i = 0; i < NA; ++i) va[i] = *(const half8*)(ga[i] + k0);
#pragma unroll
    for (int i = 0; i < NB; ++i) vb[i] = *(const half8*)(gb[i] + k0);

    for (int k = k0; k < k1; k += 64) {
        __syncthreads();               // prev iter's LDS readers done
#pragma unroll
        for (int i = 0; i < NA; ++i) *(half8*)(ldsA + loA[i]) = va[i];
#pragma unroll
        for (int i = 0; i < NB; ++i) *(half8*)(ldsB + loB[i]) = vb[i];
        if (k + 64 < k1) {             // issue next tile's loads; they fly
#pragma unroll                         // during this iter's compute phase
            for (int i = 0; i < NA; ++i) va[i] = *(const half8*)(ga[i] + k + 64);
#pragma unroll
            for (int i = 0; i < NB; ++i) vb[i] = *(const half8*)(gb[i] + k + 64);
        }
        __syncthreads();               // LDS writes visible

#pragma unroll
        for (int h = 0; h < 2; ++h) {
            half8 af[FM], bf[FN];
#pragma unroll
            for (int i = 0; i < FM; ++i) af[i] = *(const half8*)(ldsA + offA[h][i]);
#pragma unroll
            for (int i = 0; i < FN; ++i) bf[i] = *(const half8*)(ldsB + offB[h][i]);
#pragma unroll
            for (int mi = 0; mi < FM; ++mi)
#pragma unroll
                for (int ni = 0; ni < FN; ++ni) {
                    if constexpr (SWAP)
                        acc[mi][ni] = __builtin_amdgcn_mfma_f32_16x16x32_f16(
                            bf[ni], af[mi], acc[mi][ni], 0, 0, 0);
                    else
                        acc[mi][ni] = __builtin_amdgcn_mfma_f32_16x16x32_f16(
                            af[mi], bf[ni], acc[mi][ni], 0, 0, 0);
                }
        }
    }
}

// ---------------------------------------------------------------------------
// 256x128 counted-vmcnt core (qkv) — unchanged from R10 (proven).
// ---------------------------------------------------------------------------
__device__ __forceinline__ void gload_lds16(const void* g, void* l)
{
    __builtin_amdgcn_global_load_lds(
        (const __attribute__((address_space(1))) void*)g,
        (__attribute__((address_space(3))) void*)l, 16, 0, 0);
}

template<bool SWAP>
__device__ __forceinline__ void gemm_nt_256x128(
    const _Float16* __restrict__ A, const _Float16* __restrict__ B,
    const int lda, const int ldb, const int kTiles,   // kTiles even, >= 4
    _Float16* lds, f32x4 acc[4][4])
{
    const int t    = threadIdx.x;
    const int lane = t & 63;
    const int w    = t >> 6;
    const int wm   = w & 3;          // M quarter (64 rows)
    const int wn   = w >> 2;         // N half (64 cols)
    const int lr   = lane & 15;
    const int lq   = lane >> 4;

    const int r0 = t >> 3;                       // 0..63 within a slot
    const int c0 = (t & 7) ^ (r0 & 7);
    const _Float16* gA = A + (size_t)r0 * lda + c0 * 8;
    const _Float16* gB = B + (size_t)r0 * ldb + c0 * 8;

    char* ldsc = (char*)lds;
    char* stA = ldsc + w * 1024;              // + BUF*32768 + slot*8192
    char* stB = ldsc + 65536 + w * 1024;      // + BUF*16384 + slot*8192

    const int x0 = ((0 + lq) ^ (lr & 7)) * 16;
    const int x1 = ((4 + lq) ^ (lr & 7)) * 16;
    const char* rdA = ldsc + wm * 8192 + lr * 128;           // + BUF*32768 + mi*2048
    const char* rdB = ldsc + 65536 + wn * 8192 + lr * 128;   // + BUF*16384 + ni*2048

    half8 af[4][2], bf01[2][2], bf23[2][2];

#define STGA1(BUF, S, KOFF)                                                   \
    gload_lds16(gA + (size_t)(S) * 64 * lda + (KOFF),                         \
                stA + (BUF) * 32768 + (S) * 8192)

#define STGB1(BUF, S, KOFF)                                                   \
    gload_lds16(gB + (size_t)(S) * 64 * ldb + (KOFF),                         \
                stB + (BUF) * 16384 + (S) * 8192)

#define LDA_ALL(BUF) do {                                                     \
    const char* _p = rdA + (BUF) * 32768;                                     \
    _Pragma("unroll")                                                         \
    for (int mi = 0; mi < 4; ++mi) {                                          \
        af[mi][0] = *(const half8*)(_p + mi * 2048 + x0);                     \
        af[mi][1] = *(const half8*)(_p + mi * 2048 + x1);                     \
    }                                                                         \
} while (0)

#define LDB_H(DST, BUF, NQ) do {                                              \
    const char* _p = rdB + (BUF) * 16384 + (NQ) * 4096;                       \
    _Pragma("unroll")                                                         \
    for (int ni = 0; ni < 2; ++ni) {                                          \
        DST[ni][0] = *(const half8*)(_p + ni * 2048 + x0);                    \
        DST[ni][1] = *(const half8*)(_p + ni * 2048 + x1);                    \
    }                                                                         \
} while (0)

#define MFMA_NH(NQ, BSRC) do {                                                \
    _Pragma("unroll")                                                         \
    for (int mi = 0; mi < 4; ++mi)                                            \
    _Pragma("unroll")                                                         \
    for (int ni = 0; ni < 2; ++ni)                                            \
    _Pragma("unroll")                                                         \
    for (int kh = 0; kh < 2; ++kh) {                                          \
        if constexpr (SWAP)                                                   \
            acc[mi][(NQ)*2+ni] = __builtin_amdgcn_mfma_f32_16x16x32_f16(      \
                BSRC[ni][kh], af[mi][kh], acc[mi][(NQ)*2+ni], 0, 0, 0);       \
        else                                                                  \
            acc[mi][(NQ)*2+ni] = __builtin_amdgcn_mfma_f32_16x16x32_f16(      \
                af[mi][kh], BSRC[ni][kh], acc[mi][(NQ)*2+ni], 0, 0, 0);       \
    }                                                                         \
} while (0)

#define PH_PRE() do {                                                         \
    asm volatile("" ::: "memory");                                            \
    __builtin_amdgcn_s_barrier();                                             \
    asm volatile("s_waitcnt lgkmcnt(0)" ::: "memory");                        \
    __builtin_amdgcn_sched_barrier(0);                                        \
    __builtin_amdgcn_s_setprio(1);                                            \
} while (0)

#define PH_POST() do {                                                        \
    __builtin_amdgcn_s_setprio(0);                                            \
    __builtin_amdgcn_sched_barrier(0);                                        \
    __builtin_amdgcn_s_barrier();                                             \
    asm volatile("" ::: "memory");                                            \
} while (0)

#define KTILE(KT, BUF) do {                                                   \
    const int _k1 = ((KT) + 1) * 64, _k2 = ((KT) + 2) * 64;                   \
    const bool _s1 = (KT) + 1 < kTiles, _s2 = (KT) + 2 < kTiles;              \
    /* ph1 */                                                                 \
    LDA_ALL(BUF);                                                             \
    LDB_H(bf01, BUF, 0);                                                      \
    if (_s1) { STGB1((BUF) ^ 1, 0, _k1); STGB1((BUF) ^ 1, 1, _k1); }          \
    PH_PRE(); MFMA_NH(0, bf01); PH_POST();                                    \
    /* ph2 */                                                                 \
    LDB_H(bf23, BUF, 1);                                                      \
    if (_s2) { STGA1(BUF, 0, _k2); STGA1(BUF, 1, _k2);                        \
               STGA1(BUF, 2, _k2); STGA1(BUF, 3, _k2); }                      \
    asm volatile("" ::: "memory");                                            \
    __builtin_amdgcn_s_barrier();                                             \
    asm volatile("s_waitcnt lgkmcnt(0)" ::: "memory");                        \
    __builtin_amdgcn_sched_barrier(0);                                        \
    __builtin_amdgcn_s_setprio(1);                                            \
    MFMA_NH(1, bf23);                                                         \
    __builtin_amdgcn_s_setprio(0);                                            \
    if (_s2) asm volatile("s_waitcnt vmcnt(4)" ::: "memory");                 \
    else     asm volatile("s_waitcnt vmcnt(0)" ::: "memory");                 \
    __builtin_amdgcn_sched_barrier(0);                                        \
    __builtin_amdgcn_s_barrier();                                             \
    asm volatile("" ::: "memory");                                            \
} while (0)

    // prologue: tile0 fully (6 loads), then tile1's A (4 loads);
    // vmcnt(4) drains tile0, keeps tile1's A in flight.
    STGA1(0, 0, 0); STGA1(0, 1, 0); STGA1(0, 2, 0); STGA1(0, 3, 0);
    STGB1(0, 0, 0); STGB1(0, 1, 0);
    if (kTiles > 1) { STGA1(1, 0, 64); STGA1(1, 1, 64);
                      STGA1(1, 2, 64); STGA1(1, 3, 64); }
    if (kTiles > 1) asm volatile("s_waitcnt vmcnt(4)" ::: "memory");
    else            asm volatile("s_waitcnt vmcnt(0)" ::: "memory");
    __builtin_amdgcn_sched_barrier(0);
    __builtin_amdgcn_s_barrier();
    asm volatile("" ::: "memory");

#pragma unroll 1
    for (int kt = 0; kt < kTiles; kt += 2) {
        KTILE(kt, 0);
        KTILE(kt + 1, 1);
    }

#undef STGA1
#undef STGB1
#undef LDA_ALL
#undef LDB_H
#undef MFMA_NH
#undef PH_PRE
#undef PH_POST
#undef KTILE
}

// ---------------------------------------------------------------------------
// Merged f32->f16 conversion: x (8M elems) then Wq|Wk|Wv (3x1M) -> Wh.
// Also zeroes rsum[8192] (threads g<2048 write float4 zeros).
// ---------------------------------------------------------------------------
__global__ __launch_bounds__(256) void convert_k(
    const float* __restrict__ x, const float* __restrict__ Wq,
    const float* __restrict__ Wk, const float* __restrict__ Wv,
    _Float16* __restrict__ xh, _Float16* __restrict__ Wh,
    float* __restrict__ rsum)
{
    int g = blockIdx.x * 256 + threadIdx.x;
    if (g < 2048) {
        f32x4 z = { 0.f, 0.f, 0.f, 0.f };
        *(f32x4*)(rsum + g * 4) = z;
    }
    int i = g * 4;
    const float* src;
    _Float16* dst;
    if (i < 8388608) {                       // 4*2048*1024
        src = x + i; dst = xh + i;
    } else {
        int j = i - 8388608;                 // 0 .. 3*1048576
        int wsel = j >> 20;                  // each W is 2^20 elements
        int off  = j & 1048575;
        src = (wsel == 0 ? Wq : wsel == 1 ? Wk : Wv) + off;
        dst = Wh + j;
    }
    float4 f = *(const float4*)src;
    half4 h = { (_Float16)f.x, (_Float16)f.y, (_Float16)f.z, (_Float16)f.w };
    *(half4*)dst = h;
}

// ---------------------------------------------------------------------------
// Fused QKV on the 256x128 core: grid (32,8,3) = 768 blocks = 3.0 exact
// rounds on 256 CUs. z=0 Q[t][d], z=1 K[s][d] (SWAP, half4 along d);
// z=2 Vt[b][d][t] (non-SWAP, half4 along t).
// ---------------------------------------------------------------------------
__global__ __launch_bounds__(512, 2) void qkv_gemm256_k(
    const _Float16* __restrict__ xh, const _Float16* __restrict__ Wh,
    _Float16* __restrict__ Q, _Float16* __restrict__ K,
    _Float16* __restrict__ Vt)
{
    __shared__ __align__(16) _Float16 lds[49152];   // 96 KiB
    const int tileM = blockIdx.x * 256;
    const int tileN = blockIdx.y * 128;
    const int z     = blockIdx.z;
    const _Float16* W = Wh + (size_t)z * 1024 * 1024;

    const int lane = threadIdx.x & 63;
    const int w    = threadIdx.x >> 6;
    const int wm = w & 3, wn = w >> 2;
    const int lr = lane & 15, lq = lane >> 4;

    f32x4 acc[4][4] = {};
    if (z == 2) {
        gemm_nt_256x128<false>(xh + (size_t)tileM * 1024,
                               W + (size_t)tileN * 1024,
                               1024, 1024, 16, lds, acc);
#pragma unroll
        for (int mi = 0; mi < 4; ++mi)
#pragma unroll
            for (int ni = 0; ni < 4; ++ni) {
                int m0 = tileM + wm * 64 + mi * 16 + lq * 4;
                int n  = tileN + wn * 64 + ni * 16 + lr;
                int b = m0 >> 11, tt = m0 & 2047;
                half4 h = { (_Float16)acc[mi][ni][0], (_Float16)acc[mi][ni][1],
                            (_Float16)acc[mi][ni][2], (_Float16)acc[mi][ni][3] };
                *(half4*)(Vt + (size_t)b * 2048 * 1024 + (size_t)n * 2048 + tt) = h;
            }
    } else {
        gemm_nt_256x128<true>(xh + (size_t)tileM * 1024,
                              W + (size_t)tileN * 1024,
                              1024, 1024, 16, lds, acc);
        _Float16* O = (z == 0) ? Q : K;
#pragma unroll
        for (int mi = 0; mi < 4; ++mi)
#pragma unroll
            for (int ni = 0; ni < 4; ++ni) {
                int tt = tileM + wm * 64 + mi * 16 + lr;
                int d0 = tileN + wn * 64 + ni * 16 + lq * 4;
                half4 h = { (_Float16)acc[mi][ni][0], (_Float16)acc[mi][ni][1],
                            (_Float16)acc[mi][ni][2], (_Float16)acc[mi][ni][3] };
                *(half4*)(O + (size_t)tt * 1024 + d0) = h;
            }
    }
}

// ---------------------------------------------------------------------------
// Scores: DENSE triangular grid, 544 blocks, 1-D launch, XCD chunk swizzle
// (544=68x8). Writes E = exp(x*scale - 6) (masked -> 0; constant-shift
// softmax, verified R12-R14) + atomic row-sums into rsum.
// launch_bounds(256,4): VGPR<=128 cap (84 measured) -> 4 blocks/CU TLP.
// ---------------------------------------------------------------------------
__global__ __launch_bounds__(256, 4) void scores_gemm_k(
    const _Float16* __restrict__ Q, const _Float16* __restrict__ K,
    _Float16* __restrict__ S, float* __restrict__ rsum)
{
    // triangular decode
    const int bid = blockIdx.x;
    const int n   = (bid & 7) * 68 + (bid >> 3);   // bijective swizzle
    const int b   = n / 136;
    const int m   = n - b * 136;
    int ti = (int)((sqrtf(8.f * (float)m + 1.f) - 1.f) * 0.5f);
    while ((ti + 1) * (ti + 2) / 2 <= m) ++ti;     // fixup (float safety)
    while (ti * (ti + 1) / 2 > m) --ti;
    const int si = m - ti * (ti + 1) / 2;
    const int tileT = ti * 128, tileS = si * 128;

    __shared__ __align__(16) _Float16 ldsA[128 * 64];
    __shared__ __align__(16) _Float16 ldsB[128 * 64];
    f32x4 acc[4][4] = {};
    gemm_nt_core<128, 128, 2, 2, true>(
        Q + (size_t)b * 2048 * 1024 + (size_t)tileT * 1024,
        K + (size_t)b * 2048 * 1024 + (size_t)tileS * 1024,
        1024, 1024, 0, 1024, ldsA, ldsB, acc);

    const int lane = threadIdx.x & 63;
    const int w    = threadIdx.x >> 6;
    const int wm = w & 1, wn = w >> 1;
    const int lr = lane & 15, lq = lane >> 4;
    const float scale = 0.03125f;  // 1024^-0.5

    float rp[4] = { 0.f, 0.f, 0.f, 0.f };
#pragma unroll
    for (int mi = 0; mi < 4; ++mi)
#pragma unroll
        for (int ni = 0; ni < 4; ++ni) {
            int tt = tileT + wm * 64 + mi * 16 + lr;
            int s0 = tileS + wn * 64 + ni * 16 + lq * 4;
            half4 h;
#pragma unroll
            for (int r = 0; r < 4; ++r) {
                float e = __expf(fmaf(acc[mi][ni][r], scale, -6.0f));
                h[r] = (s0 + r <= tt) ? (_Float16)e : (_Float16)0.f;
                rp[mi] += (float)h[r];
            }
            *(half4*)(S + ((size_t)b * 2048 + tt) * 2048 + s0) = h;
        }

    // fold the 4 lq-lanes holding the same row (lane bits 4,5)
#pragma unroll
    for (int mi = 0; mi < 4; ++mi) {
        rp[mi] += __shfl_xor(rp[mi], 16);
        rp[mi] += __shfl_xor(rp[mi], 32);
    }
    if (lq == 0) {
#pragma unroll
        for (int mi = 0; mi < 4; ++mi) {
            int tt = tileT + wm * 64 + mi * 16 + lr;
            atomicAdd(&rsum[(size_t)b * 2048 + tt], rp[mi]);
        }
    }
}

// ---------------------------------------------------------------------------
// PV: 128(t) x 128(d) tiles, 1-D grid 512 with bijective XCD chunk swizzle
// (512=64x8): n=(bid&7)*64 + bid>>3 -> XCD k owns n in [64k,64k+64) =
// 4 complete (b,d) Vt-panel groups (16 t-blocks each). Decode: t fastest
// within a (b,d) group so the 16 blocks sharing a Vt panel are contiguous
// -> panel lands in ONE XCD L2 (512 KB x 4 = 2 MB < 4 MB). Longest-t
// first within groups. A = E (unnorm exp), epilogue divides by rsum[t].
// launch_bounds(256,4): 4 blocks/CU TLP for the cache-latency-bound loop.
// ---------------------------------------------------------------------------
__global__ __launch_bounds__(256, 4) void pv_gemm_k(
    const _Float16* __restrict__ P, const _Float16* __restrict__ Vt,
    const float* __restrict__ rsum, float* __restrict__ out)
{
    __shared__ __align__(16) _Float16 ldsA[128 * 64];
    __shared__ __align__(16) _Float16 ldsB[128 * 64];
    const int bid = blockIdx.x;
    const int n   = (bid & 7) * 64 + (bid >> 3);   // XCD chunk swizzle
    const int tio = n & 15;
    const int d   = (n >> 4) & 7;
    const int b   = n >> 7;
    const int tileT = (15 - tio) * 128;            // longest-first
    const int tileD = d * 128;
    const int kEnd  = tileT + 128;

    f32x4 acc[4][4] = {};
    gemm_nt_core<128, 128, 2, 2, true>(
        P + ((size_t)b * 2048 + tileT) * 2048,
        Vt + (size_t)b * 1024 * 2048 + (size_t)tileD * 2048,
        2048, 2048, 0, kEnd, ldsA, ldsB, acc);

    const int lane = threadIdx.x & 63;
    const int w    = threadIdx.x >> 6;
    const int wm = w & 1, wn = w >> 1;
    const int lr = lane & 15, lq = lane >> 4;

#pragma unroll
    for (int mi = 0; mi < 4; ++mi) {
        const int tt = tileT + wm * 64 + mi * 16 + lr;
        const float inv = 1.0f / rsum[(size_t)b * 2048 + tt];
#pragma unroll
        for (int ni = 0; ni < 4; ++ni) {
            int d0 = tileD + wn * 64 + ni * 16 + lq * 4;
            f32x4 o = { acc[mi][ni][0] * inv, acc[mi][ni][1] * inv,
                        acc[mi][ni][2] * inv, acc[mi][ni][3] * inv };
            *(f32x4*)(out + ((size_t)b * 2048 + tt) * 1024 + d0) = o;
        }
    }
}

// ---------------------------------------------------------------------------
extern "C" void kernel_launch(void* const* d_in, const int* in_sizes, int n_in,
                              void* d_out, int out_size, void* d_ws, size_t ws_size,
                              hipStream_t stream)
{
    const float* x  = (const float*)d_in[0];
    const float* Wq = (const float*)d_in[1];
    const float* Wk = (const float*)d_in[2];
    const float* Wv = (const float*)d_in[3];
    float* out = (float*)d_out;

    char* ws = (char*)d_ws;
    // layout (MB): xh 0..16 | Wh 16..22 | Q 22..38 | K 38..54 | Vt 54..70 |
    // S16 70..102 | rsum 102..102.03.  Total ~102.1 MB.
    _Float16* xh = (_Float16*)(ws);
    _Float16* Wh = (_Float16*)(ws + (16u << 20));
    _Float16* Qh = (_Float16*)(ws + (22u << 20));
    _Float16* Kh = (_Float16*)(ws + (38u << 20));
    _Float16* Vt = (_Float16*)(ws + (54u << 20));
    _Float16* S  = (_Float16*)(ws + (70u << 20));
    float*    rs = (float*)   (ws + (102u << 20));

    convert_k<<<11264, 256, 0, stream>>>(x, Wq, Wk, Wv, xh, Wh, rs);

    qkv_gemm256_k<<<dim3(32, 8, 3), 512, 0, stream>>>(xh, Wh, Qh, Kh, Vt);

    scores_gemm_k<<<544, 256, 0, stream>>>(Qh, Kh, S, rs);
    pv_gemm_k<<<512, 256, 0, stream>>>(S, Vt, rs, out);
}

// Round 10
// 235.544 us; speedup vs baseline: 1.8219x; 1.3634x over previous
//
#include <hip/hip_runtime.h>
#include <hip/hip_fp16.h>

// B=4, T=2048, C=1024. Single-head causal attention, fp32 in/out.
// Internals fp16 (MFMA f32_16x16x32_f16), fp32 accum + fp32 softmax math.
// R18: revert R17's __launch_bounds__(256,4) on scores/pv — it clamped
// VGPR to 64 (counter-verified) and spilled the reg-staged core to
// scratch (scores 97-204 us, MfmaUtil <7%). Registers > occupancy for
// this core (Guideline 6). Keep ONLY the pv XCD chunk swizzle from R17
// (index arithmetic, zero codegen impact): each XCD owns 4 complete
// (b,d) Vt-panel groups (2 MB < 4 MB L2) instead of all 8 XCDs pulling
// every panel. Everything else byte-identical to R14 (235.4 us proven).

typedef __attribute__((ext_vector_type(8))) _Float16 half8;
typedef __attribute__((ext_vector_type(4))) _Float16 half4;
typedef __attribute__((ext_vector_type(4))) float f32x4;

// ---------------------------------------------------------------------------
// NT-GEMM core (scores / pv), reg-staged prefetch. TM x TN tile, BK=64,
// 256 thr = WM*WN waves. LDS swizzle verified 0 conflicts.
// ---------------------------------------------------------------------------
template<int TM, int TN, int WM, int WN, bool SWAP>
__device__ __forceinline__ void gemm_nt_core(
    const _Float16* __restrict__ A, const _Float16* __restrict__ B,
    int lda, int ldb, int k0, int k1,
    _Float16* ldsA, _Float16* ldsB,      // TM*64, TN*64 halves
    f32x4 acc[TM / (WM * 16)][TN / (WN * 16)])
{
    constexpr int FM = TM / (WM * 16), FN = TN / (WN * 16);
    constexpr int NA = TM / 32, NB = TN / 32;   // 16B chunks per thread
    const int t    = threadIdx.x;
    const int lane = t & 63;
    const int w    = t >> 6;
    const int wm   = w % WM;
    const int wn   = w / WM;
    const int lr   = lane & 15;
    const int lq   = lane >> 4;

    const _Float16* ga[NA]; int loA[NA];
    const _Float16* gb[NB]; int loB[NB];
#pragma unroll
    for (int i = 0; i < NA; ++i) {
        int f = t + 256 * i;
        int r = f >> 3, c = (f & 7) ^ ((f >> 3) & 7);
        ga[i] = A + (size_t)r * lda + c * 8;
        loA[i] = f * 8;
    }
#pragma unroll
    for (int i = 0; i < NB; ++i) {
        int f = t + 256 * i;
        int r = f >> 3, c = (f & 7) ^ ((f >> 3) & 7);
        gb[i] = B + (size_t)r * ldb + c * 8;
        loB[i] = f * 8;
    }

    int offA[2][FM], offB[2][FN];
#pragma unroll
    for (int h = 0; h < 2; ++h) {
#pragma unroll
        for (int i = 0; i < FM; ++i) {
            int R = wm * (TM / WM) + i * 16 + lr;
            offA[h][i] = (8 * R + ((h * 4 + lq) ^ (R & 7))) * 8;
        }
#pragma unroll
        for (int i = 0; i < FN; ++i) {
            int R = wn * (TN / WN) + i * 16 + lr;
            offB[h][i] = (8 * R + ((h * 4 + lq) ^ (R & 7))) * 8;
        }
    }

    // prologue: tile k0 -> registers
    half8 va[NA], vb[NB];
#pragma unroll
    for (int i = 0; i < NA; ++i) va[i] = *(const half8*)(ga[i] + k0);
#pragma unroll
    for (int i = 0; i < NB; ++i) vb[i] = *(const half8*)(gb[i] + k0);

    for (int k = k0; k < k1; k += 64) {
        __syncthreads();               // prev iter's LDS readers done
#pragma unroll
        for (int i = 0; i < NA; ++i) *(half8*)(ldsA + loA[i]) = va[i];
#pragma unroll
        for (int i = 0; i < NB; ++i) *(half8*)(ldsB + loB[i]) = vb[i];
        if (k + 64 < k1) {             // issue next tile's loads; they fly
#pragma unroll                         // during this iter's compute phase
            for (int i = 0; i < NA; ++i) va[i] = *(const half8*)(ga[i] + k + 64);
#pragma unroll
            for (int i = 0; i < NB; ++i) vb[i] = *(const half8*)(gb[i] + k + 64);
        }
        __syncthreads();               // LDS writes visible

#pragma unroll
        for (int h = 0; h < 2; ++h) {
            half8 af[FM], bf[FN];
#pragma unroll
            for (int i = 0; i < FM; ++i) af[i] = *(const half8*)(ldsA + offA[h][i]);
#pragma unroll
            for (int i = 0; i < FN; ++i) bf[i] = *(const half8*)(ldsB + offB[h][i]);
#pragma unroll
            for (int mi = 0; mi < FM; ++mi)
#pragma unroll
                for (int ni = 0; ni < FN; ++ni) {
                    if constexpr (SWAP)
                        acc[mi][ni] = __builtin_amdgcn_mfma_f32_16x16x32_f16(
                            bf[ni], af[mi], acc[mi][ni], 0, 0, 0);
                    else
                        acc[mi][ni] = __builtin_amdgcn_mfma_f32_16x16x32_f16(
                            af[mi], bf[ni], acc[mi][ni], 0, 0, 0);
                }
        }
    }
}

// ---------------------------------------------------------------------------
// 256x128 counted-vmcnt core (qkv) — unchanged from R10 (proven).
// ---------------------------------------------------------------------------
__device__ __forceinline__ void gload_lds16(const void* g, void* l)
{
    __builtin_amdgcn_global_load_lds(
        (const __attribute__((address_space(1))) void*)g,
        (__attribute__((address_space(3))) void*)l, 16, 0, 0);
}

template<bool SWAP>
__device__ __forceinline__ void gemm_nt_256x128(
    const _Float16* __restrict__ A, const _Float16* __restrict__ B,
    const int lda, const int ldb, const int kTiles,   // kTiles even, >= 4
    _Float16* lds, f32x4 acc[4][4])
{
    const int t    = threadIdx.x;
    const int lane = t & 63;
    const int w    = t >> 6;
    const int wm   = w & 3;          // M quarter (64 rows)
    const int wn   = w >> 2;         // N half (64 cols)
    const int lr   = lane & 15;
    const int lq   = lane >> 4;

    const int r0 = t >> 3;                       // 0..63 within a slot
    const int c0 = (t & 7) ^ (r0 & 7);
    const _Float16* gA = A + (size_t)r0 * lda + c0 * 8;
    const _Float16* gB = B + (size_t)r0 * ldb + c0 * 8;

    char* ldsc = (char*)lds;
    char* stA = ldsc + w * 1024;              // + BUF*32768 + slot*8192
    char* stB = ldsc + 65536 + w * 1024;      // + BUF*16384 + slot*8192

    const int x0 = ((0 + lq) ^ (lr & 7)) * 16;
    const int x1 = ((4 + lq) ^ (lr & 7)) * 16;
    const char* rdA = ldsc + wm * 8192 + lr * 128;           // + BUF*32768 + mi*2048
    const char* rdB = ldsc + 65536 + wn * 8192 + lr * 128;   // + BUF*16384 + ni*2048

    half8 af[4][2], bf01[2][2], bf23[2][2];

#define STGA1(BUF, S, KOFF)                                                   \
    gload_lds16(gA + (size_t)(S) * 64 * lda + (KOFF),                         \
                stA + (BUF) * 32768 + (S) * 8192)

#define STGB1(BUF, S, KOFF)                                                   \
    gload_lds16(gB + (size_t)(S) * 64 * ldb + (KOFF),                         \
                stB + (BUF) * 16384 + (S) * 8192)

#define LDA_ALL(BUF) do {                                                     \
    const char* _p = rdA + (BUF) * 32768;                                     \
    _Pragma("unroll")                                                         \
    for (int mi = 0; mi < 4; ++mi) {                                          \
        af[mi][0] = *(const half8*)(_p + mi * 2048 + x0);                     \
        af[mi][1] = *(const half8*)(_p + mi * 2048 + x1);                     \
    }                                                                         \
} while (0)

#define LDB_H(DST, BUF, NQ) do {                                              \
    const char* _p = rdB + (BUF) * 16384 + (NQ) * 4096;                       \
    _Pragma("unroll")                                                         \
    for (int ni = 0; ni < 2; ++ni) {                                          \
        DST[ni][0] = *(const half8*)(_p + ni * 2048 + x0);                    \
        DST[ni][1] = *(const half8*)(_p + ni * 2048 + x1);                    \
    }                                                                         \
} while (0)

#define MFMA_NH(NQ, BSRC) do {                                                \
    _Pragma("unroll")                                                         \
    for (int mi = 0; mi < 4; ++mi)                                            \
    _Pragma("unroll")                                                         \
    for (int ni = 0; ni < 2; ++ni)                                            \
    _Pragma("unroll")                                                         \
    for (int kh = 0; kh < 2; ++kh) {                                          \
        if constexpr (SWAP)                                                   \
            acc[mi][(NQ)*2+ni] = __builtin_amdgcn_mfma_f32_16x16x32_f16(      \
                BSRC[ni][kh], af[mi][kh], acc[mi][(NQ)*2+ni], 0, 0, 0);       \
        else                                                                  \
            acc[mi][(NQ)*2+ni] = __builtin_amdgcn_mfma_f32_16x16x32_f16(      \
                af[mi][kh], BSRC[ni][kh], acc[mi][(NQ)*2+ni], 0, 0, 0);       \
    }                                                                         \
} while (0)

#define PH_PRE() do {                                                         \
    asm volatile("" ::: "memory");                                            \
    __builtin_amdgcn_s_barrier();                                             \
    asm volatile("s_waitcnt lgkmcnt(0)" ::: "memory");                        \
    __builtin_amdgcn_sched_barrier(0);                                        \
    __builtin_amdgcn_s_setprio(1);                                            \
} while (0)

#define PH_POST() do {                                                        \
    __builtin_amdgcn_s_setprio(0);                                            \
    __builtin_amdgcn_sched_barrier(0);                                        \
    __builtin_amdgcn_s_barrier();                                             \
    asm volatile("" ::: "memory");                                            \
} while (0)

#define KTILE(KT, BUF) do {                                                   \
    const int _k1 = ((KT) + 1) * 64, _k2 = ((KT) + 2) * 64;                   \
    const bool _s1 = (KT) + 1 < kTiles, _s2 = (KT) + 2 < kTiles;              \
    /* ph1 */                                                                 \
    LDA_ALL(BUF);                                                             \
    LDB_H(bf01, BUF, 0);                                                      \
    if (_s1) { STGB1((BUF) ^ 1, 0, _k1); STGB1((BUF) ^ 1, 1, _k1); }          \
    PH_PRE(); MFMA_NH(0, bf01); PH_POST();                                    \
    /* ph2 */                                                                 \
    LDB_H(bf23, BUF, 1);                                                      \
    if (_s2) { STGA1(BUF, 0, _k2); STGA1(BUF, 1, _k2);                        \
               STGA1(BUF, 2, _k2); STGA1(BUF, 3, _k2); }                      \
    asm volatile("" ::: "memory");                                            \
    __builtin_amdgcn_s_barrier();                                             \
    asm volatile("s_waitcnt lgkmcnt(0)" ::: "memory");                        \
    __builtin_amdgcn_sched_barrier(0);                                        \
    __builtin_amdgcn_s_setprio(1);                                            \
    MFMA_NH(1, bf23);                                                         \
    __builtin_amdgcn_s_setprio(0);                                            \
    if (_s2) asm volatile("s_waitcnt vmcnt(4)" ::: "memory");                 \
    else     asm volatile("s_waitcnt vmcnt(0)" ::: "memory");                 \
    __builtin_amdgcn_sched_barrier(0);                                        \
    __builtin_amdgcn_s_barrier();                                             \
    asm volatile("" ::: "memory");                                            \
} while (0)

    // prologue: tile0 fully (6 loads), then tile1's A (4 loads);
    // vmcnt(4) drains tile0, keeps tile1's A in flight.
    STGA1(0, 0, 0); STGA1(0, 1, 0); STGA1(0, 2, 0); STGA1(0, 3, 0);
    STGB1(0, 0, 0); STGB1(0, 1, 0);
    if (kTiles > 1) { STGA1(1, 0, 64); STGA1(1, 1, 64);
                      STGA1(1, 2, 64); STGA1(1, 3, 64); }
    if (kTiles > 1) asm volatile("s_waitcnt vmcnt(4)" ::: "memory");
    else            asm volatile("s_waitcnt vmcnt(0)" ::: "memory");
    __builtin_amdgcn_sched_barrier(0);
    __builtin_amdgcn_s_barrier();
    asm volatile("" ::: "memory");

#pragma unroll 1
    for (int kt = 0; kt < kTiles; kt += 2) {
        KTILE(kt, 0);
        KTILE(kt + 1, 1);
    }

#undef STGA1
#undef STGB1
#undef LDA_ALL
#undef LDB_H
#undef MFMA_NH
#undef PH_PRE
#undef PH_POST
#undef KTILE
}

// ---------------------------------------------------------------------------
// Merged f32->f16 conversion: x (8M elems) then Wq|Wk|Wv (3x1M) -> Wh.
// Also zeroes rsum[8192] (threads g<2048 write float4 zeros).
// ---------------------------------------------------------------------------
__global__ __launch_bounds__(256) void convert_k(
    const float* __restrict__ x, const float* __restrict__ Wq,
    const float* __restrict__ Wk, const float* __restrict__ Wv,
    _Float16* __restrict__ xh, _Float16* __restrict__ Wh,
    float* __restrict__ rsum)
{
    int g = blockIdx.x * 256 + threadIdx.x;
    if (g < 2048) {
        f32x4 z = { 0.f, 0.f, 0.f, 0.f };
        *(f32x4*)(rsum + g * 4) = z;
    }
    int i = g * 4;
    const float* src;
    _Float16* dst;
    if (i < 8388608) {                       // 4*2048*1024
        src = x + i; dst = xh + i;
    } else {
        int j = i - 8388608;                 // 0 .. 3*1048576
        int wsel = j >> 20;                  // each W is 2^20 elements
        int off  = j & 1048575;
        src = (wsel == 0 ? Wq : wsel == 1 ? Wk : Wv) + off;
        dst = Wh + j;
    }
    float4 f = *(const float4*)src;
    half4 h = { (_Float16)f.x, (_Float16)f.y, (_Float16)f.z, (_Float16)f.w };
    *(half4*)dst = h;
}

// ---------------------------------------------------------------------------
// Fused QKV on the 256x128 core: grid (32,8,3) = 768 blocks = 3.0 exact
// rounds on 256 CUs. z=0 Q[t][d], z=1 K[s][d] (SWAP, half4 along d);
// z=2 Vt[b][d][t] (non-SWAP, half4 along t).
// ---------------------------------------------------------------------------
__global__ __launch_bounds__(512, 2) void qkv_gemm256_k(
    const _Float16* __restrict__ xh, const _Float16* __restrict__ Wh,
    _Float16* __restrict__ Q, _Float16* __restrict__ K,
    _Float16* __restrict__ Vt)
{
    __shared__ __align__(16) _Float16 lds[49152];   // 96 KiB
    const int tileM = blockIdx.x * 256;
    const int tileN = blockIdx.y * 128;
    const int z     = blockIdx.z;
    const _Float16* W = Wh + (size_t)z * 1024 * 1024;

    const int lane = threadIdx.x & 63;
    const int w    = threadIdx.x >> 6;
    const int wm = w & 3, wn = w >> 2;
    const int lr = lane & 15, lq = lane >> 4;

    f32x4 acc[4][4] = {};
    if (z == 2) {
        gemm_nt_256x128<false>(xh + (size_t)tileM * 1024,
                               W + (size_t)tileN * 1024,
                               1024, 1024, 16, lds, acc);
#pragma unroll
        for (int mi = 0; mi < 4; ++mi)
#pragma unroll
            for (int ni = 0; ni < 4; ++ni) {
                int m0 = tileM + wm * 64 + mi * 16 + lq * 4;
                int n  = tileN + wn * 64 + ni * 16 + lr;
                int b = m0 >> 11, tt = m0 & 2047;
                half4 h = { (_Float16)acc[mi][ni][0], (_Float16)acc[mi][ni][1],
                            (_Float16)acc[mi][ni][2], (_Float16)acc[mi][ni][3] };
                *(half4*)(Vt + (size_t)b * 2048 * 1024 + (size_t)n * 2048 + tt) = h;
            }
    } else {
        gemm_nt_256x128<true>(xh + (size_t)tileM * 1024,
                              W + (size_t)tileN * 1024,
                              1024, 1024, 16, lds, acc);
        _Float16* O = (z == 0) ? Q : K;
#pragma unroll
        for (int mi = 0; mi < 4; ++mi)
#pragma unroll
            for (int ni = 0; ni < 4; ++ni) {
                int tt = tileM + wm * 64 + mi * 16 + lr;
                int d0 = tileN + wn * 64 + ni * 16 + lq * 4;
                half4 h = { (_Float16)acc[mi][ni][0], (_Float16)acc[mi][ni][1],
                            (_Float16)acc[mi][ni][2], (_Float16)acc[mi][ni][3] };
                *(half4*)(O + (size_t)tt * 1024 + d0) = h;
            }
    }
}

// ---------------------------------------------------------------------------
// Scores: DENSE triangular grid, 544 blocks, 1-D launch, XCD chunk swizzle
// (544=68x8). Writes E = exp(x*scale - 6) (masked -> 0; constant-shift
// softmax, verified R12-R14) + atomic row-sums into rsum.
// Default launch bounds: the reg-staged core needs its ~100 VGPRs
// (R17's (256,4) clamp -> VGPR 64 -> scratch spill -> 97-204 us).
// ---------------------------------------------------------------------------
__global__ __launch_bounds__(256) void scores_gemm_k(
    const _Float16* __restrict__ Q, const _Float16* __restrict__ K,
    _Float16* __restrict__ S, float* __restrict__ rsum)
{
    // triangular decode
    const int bid = blockIdx.x;
    const int n   = (bid & 7) * 68 + (bid >> 3);   // bijective swizzle
    const int b   = n / 136;
    const int m   = n - b * 136;
    int ti = (int)((sqrtf(8.f * (float)m + 1.f) - 1.f) * 0.5f);
    while ((ti + 1) * (ti + 2) / 2 <= m) ++ti;     // fixup (float safety)
    while (ti * (ti + 1) / 2 > m) --ti;
    const int si = m - ti * (ti + 1) / 2;
    const int tileT = ti * 128, tileS = si * 128;

    __shared__ __align__(16) _Float16 ldsA[128 * 64];
    __shared__ __align__(16) _Float16 ldsB[128 * 64];
    f32x4 acc[4][4] = {};
    gemm_nt_core<128, 128, 2, 2, true>(
        Q + (size_t)b * 2048 * 1024 + (size_t)tileT * 1024,
        K + (size_t)b * 2048 * 1024 + (size_t)tileS * 1024,
        1024, 1024, 0, 1024, ldsA, ldsB, acc);

    const int lane = threadIdx.x & 63;
    const int w    = threadIdx.x >> 6;
    const int wm = w & 1, wn = w >> 1;
    const int lr = lane & 15, lq = lane >> 4;
    const float scale = 0.03125f;  // 1024^-0.5

    float rp[4] = { 0.f, 0.f, 0.f, 0.f };
#pragma unroll
    for (int mi = 0; mi < 4; ++mi)
#pragma unroll
        for (int ni = 0; ni < 4; ++ni) {
            int tt = tileT + wm * 64 + mi * 16 + lr;
            int s0 = tileS + wn * 64 + ni * 16 + lq * 4;
            half4 h;
#pragma unroll
            for (int r = 0; r < 4; ++r) {
                float e = __expf(fmaf(acc[mi][ni][r], scale, -6.0f));
                h[r] = (s0 + r <= tt) ? (_Float16)e : (_Float16)0.f;
                rp[mi] += (float)h[r];
            }
            *(half4*)(S + ((size_t)b * 2048 + tt) * 2048 + s0) = h;
        }

    // fold the 4 lq-lanes holding the same row (lane bits 4,5)
#pragma unroll
    for (int mi = 0; mi < 4; ++mi) {
        rp[mi] += __shfl_xor(rp[mi], 16);
        rp[mi] += __shfl_xor(rp[mi], 32);
    }
    if (lq == 0) {
#pragma unroll
        for (int mi = 0; mi < 4; ++mi) {
            int tt = tileT + wm * 64 + mi * 16 + lr;
            atomicAdd(&rsum[(size_t)b * 2048 + tt], rp[mi]);
        }
    }
}

// ---------------------------------------------------------------------------
// PV: 128(t) x 128(d) tiles, 1-D grid 512 with bijective XCD chunk swizzle
// (512=64x8): n=(bid&7)*64 + bid>>3 -> XCD k owns 4 complete (b,d)
// Vt-panel groups (16 t-blocks each, t fastest so the 16 blocks sharing a
// Vt panel are contiguous on ONE XCD; 4 panels = 2 MB < 4 MB L2).
// Longest-t first within groups. Default launch bounds (no VGPR clamp).
// A = E (unnorm exp), epilogue divides by rsum[t].
// ---------------------------------------------------------------------------
__global__ __launch_bounds__(256) void pv_gemm_k(
    const _Float16* __restrict__ P, const _Float16* __restrict__ Vt,
    const float* __restrict__ rsum, float* __restrict__ out)
{
    __shared__ __align__(16) _Float16 ldsA[128 * 64];
    __shared__ __align__(16) _Float16 ldsB[128 * 64];
    const int bid = blockIdx.x;
    const int n   = (bid & 7) * 64 + (bid >> 3);   // XCD chunk swizzle
    const int tio = n & 15;
    const int d   = (n >> 4) & 7;
    const int b   = n >> 7;
    const int tileT = (15 - tio) * 128;            // longest-first
    const int tileD = d * 128;
    const int kEnd  = tileT + 128;

    f32x4 acc[4][4] = {};
    gemm_nt_core<128, 128, 2, 2, true>(
        P + ((size_t)b * 2048 + tileT) * 2048,
        Vt + (size_t)b * 1024 * 2048 + (size_t)tileD * 2048,
        2048, 2048, 0, kEnd, ldsA, ldsB, acc);

    const int lane = threadIdx.x & 63;
    const int w    = threadIdx.x >> 6;
    const int wm = w & 1, wn = w >> 1;
    const int lr = lane & 15, lq = lane >> 4;

#pragma unroll
    for (int mi = 0; mi < 4; ++mi) {
        const int tt = tileT + wm * 64 + mi * 16 + lr;
        const float inv = 1.0f / rsum[(size_t)b * 2048 + tt];
#pragma unroll
        for (int ni = 0; ni < 4; ++ni) {
            int d0 = tileD + wn * 64 + ni * 16 + lq * 4;
            f32x4 o = { acc[mi][ni][0] * inv, acc[mi][ni][1] * inv,
                        acc[mi][ni][2] * inv, acc[mi][ni][3] * inv };
            *(f32x4*)(out + ((size_t)b * 2048 + tt) * 1024 + d0) = o;
        }
    }
}

// ---------------------------------------------------------------------------
extern "C" void kernel_launch(void* const* d_in, const int* in_sizes, int n_in,
                              void* d_out, int out_size, void* d_ws, size_t ws_size,
                              hipStream_t stream)
{
    const float* x  = (const float*)d_in[0];
    const float* Wq = (const float*)d_in[1];
    const float* Wk = (const float*)d_in[2];
    const float* Wv = (const float*)d_in[3];
    float* out = (float*)d_out;

    char* ws = (char*)d_ws;
    // layout (MB): xh 0..16 | Wh 16..22 | Q 22..38 | K 38..54 | Vt 54..70 |
    // S16 70..102 | rsum 102..102.03.  Total ~102.1 MB.
    _Float16* xh = (_Float16*)(ws);
    _Float16* Wh = (_Float16*)(ws + (16u << 20));
    _Float16* Qh = (_Float16*)(ws + (22u << 20));
    _Float16* Kh = (_Float16*)(ws + (38u << 20));
    _Float16* Vt = (_Float16*)(ws + (54u << 20));
    _Float16* S  = (_Float16*)(ws + (70u << 20));
    float*    rs = (float*)   (ws + (102u << 20));

    convert_k<<<11264, 256, 0, stream>>>(x, Wq, Wk, Wv, xh, Wh, rs);

    qkv_gemm256_k<<<dim3(32, 8, 3), 512, 0, stream>>>(xh, Wh, Qh, Kh, Vt);

    scores_gemm_k<<<544, 256, 0, stream>>>(Qh, Kh, S, rs);
    pv_gemm_k<<<512, 256, 0, stream>>>(S, Vt, rs, out);
}

// Round 11
// 224.663 us; speedup vs baseline: 1.9101x; 1.0484x over previous
//
#include <hip/hip_runtime.h>
#include <hip/hip_fp16.h>

// B=4, T=2048, C=1024. Single-head causal attention, fp32 in/out.
// Internals fp16 (MFMA f32_16x16x32_f16), fp32 accum + fp32 softmax math.
// R19: R18 (235.5 us) + ONE change: scores epilogue store coalescing.
// R17 counters showed scores WRITE_SIZE = 77 MB vs ~18 MB ideal (4.3x):
// the SWAP epilogue's half4 stores put adjacent lanes on rows 4 KB apart
// -> every 128B line written as 32B partial-line RMW fragments. Fix:
// stage the exp-applied tile in LDS (128 x 136-pad halves, 16B-aligned
// rows, <=2-way bank alias = free) then copy out coalesced — each store
// instruction covers 4 full rows x 256B contiguous. LDS 34 KB (still 4
// blocks/CU), no launch-bounds change (R17 lesson: VGPR > occupancy).
// qkv (256x128 counted-vmcnt, 68-77 us), pv (+XCD swizzle), convert frozen.

typedef __attribute__((ext_vector_type(8))) _Float16 half8;
typedef __attribute__((ext_vector_type(4))) _Float16 half4;
typedef __attribute__((ext_vector_type(4))) float f32x4;

// ---------------------------------------------------------------------------
// NT-GEMM core (scores / pv), reg-staged prefetch. TM x TN tile, BK=64,
// 256 thr = WM*WN waves. LDS swizzle verified 0 conflicts.
// ---------------------------------------------------------------------------
template<int TM, int TN, int WM, int WN, bool SWAP>
__device__ __forceinline__ void gemm_nt_core(
    const _Float16* __restrict__ A, const _Float16* __restrict__ B,
    int lda, int ldb, int k0, int k1,
    _Float16* ldsA, _Float16* ldsB,      // TM*64, TN*64 halves
    f32x4 acc[TM / (WM * 16)][TN / (WN * 16)])
{
    constexpr int FM = TM / (WM * 16), FN = TN / (WN * 16);
    constexpr int NA = TM / 32, NB = TN / 32;   // 16B chunks per thread
    const int t    = threadIdx.x;
    const int lane = t & 63;
    const int w    = t >> 6;
    const int wm   = w % WM;
    const int wn   = w / WM;
    const int lr   = lane & 15;
    const int lq   = lane >> 4;

    const _Float16* ga[NA]; int loA[NA];
    const _Float16* gb[NB]; int loB[NB];
#pragma unroll
    for (int i = 0; i < NA; ++i) {
        int f = t + 256 * i;
        int r = f >> 3, c = (f & 7) ^ ((f >> 3) & 7);
        ga[i] = A + (size_t)r * lda + c * 8;
        loA[i] = f * 8;
    }
#pragma unroll
    for (int i = 0; i < NB; ++i) {
        int f = t + 256 * i;
        int r = f >> 3, c = (f & 7) ^ ((f >> 3) & 7);
        gb[i] = B + (size_t)r * ldb + c * 8;
        loB[i] = f * 8;
    }

    int offA[2][FM], offB[2][FN];
#pragma unroll
    for (int h = 0; h < 2; ++h) {
#pragma unroll
        for (int i = 0; i < FM; ++i) {
            int R = wm * (TM / WM) + i * 16 + lr;
            offA[h][i] = (8 * R + ((h * 4 + lq) ^ (R & 7))) * 8;
        }
#pragma unroll
        for (int i = 0; i < FN; ++i) {
            int R = wn * (TN / WN) + i * 16 + lr;
            offB[h][i] = (8 * R + ((h * 4 + lq) ^ (R & 7))) * 8;
        }
    }

    // prologue: tile k0 -> registers
    half8 va[NA], vb[NB];
#pragma unroll
    for (int i = 0; i < NA; ++i) va[i] = *(const half8*)(ga[i] + k0);
#pragma unroll
    for (int i = 0; i < NB; ++i) vb[i] = *(const half8*)(gb[i] + k0);

    for (int k = k0; k < k1; k += 64) {
        __syncthreads();               // prev iter's LDS readers done
#pragma unroll
        for (int i = 0; i < NA; ++i) *(half8*)(ldsA + loA[i]) = va[i];
#pragma unroll
        for (int i = 0; i < NB; ++i) *(half8*)(ldsB + loB[i]) = vb[i];
        if (k + 64 < k1) {             // issue next tile's loads; they fly
#pragma unroll                         // during this iter's compute phase
            for (int i = 0; i < NA; ++i) va[i] = *(const half8*)(ga[i] + k + 64);
#pragma unroll
            for (int i = 0; i < NB; ++i) vb[i] = *(const half8*)(gb[i] + k + 64);
        }
        __syncthreads();               // LDS writes visible

#pragma unroll
        for (int h = 0; h < 2; ++h) {
            half8 af[FM], bf[FN];
#pragma unroll
            for (int i = 0; i < FM; ++i) af[i] = *(const half8*)(ldsA + offA[h][i]);
#pragma unroll
            for (int i = 0; i < FN; ++i) bf[i] = *(const half8*)(ldsB + offB[h][i]);
#pragma unroll
            for (int mi = 0; mi < FM; ++mi)
#pragma unroll
                for (int ni = 0; ni < FN; ++ni) {
                    if constexpr (SWAP)
                        acc[mi][ni] = __builtin_amdgcn_mfma_f32_16x16x32_f16(
                            bf[ni], af[mi], acc[mi][ni], 0, 0, 0);
                    else
                        acc[mi][ni] = __builtin_amdgcn_mfma_f32_16x16x32_f16(
                            af[mi], bf[ni], acc[mi][ni], 0, 0, 0);
                }
        }
    }
}

// ---------------------------------------------------------------------------
// 256x128 counted-vmcnt core (qkv) — unchanged from R10 (proven).
// ---------------------------------------------------------------------------
__device__ __forceinline__ void gload_lds16(const void* g, void* l)
{
    __builtin_amdgcn_global_load_lds(
        (const __attribute__((address_space(1))) void*)g,
        (__attribute__((address_space(3))) void*)l, 16, 0, 0);
}

template<bool SWAP>
__device__ __forceinline__ void gemm_nt_256x128(
    const _Float16* __restrict__ A, const _Float16* __restrict__ B,
    const int lda, const int ldb, const int kTiles,   // kTiles even, >= 4
    _Float16* lds, f32x4 acc[4][4])
{
    const int t    = threadIdx.x;
    const int lane = t & 63;
    const int w    = t >> 6;
    const int wm   = w & 3;          // M quarter (64 rows)
    const int wn   = w >> 2;         // N half (64 cols)
    const int lr   = lane & 15;
    const int lq   = lane >> 4;

    const int r0 = t >> 3;                       // 0..63 within a slot
    const int c0 = (t & 7) ^ (r0 & 7);
    const _Float16* gA = A + (size_t)r0 * lda + c0 * 8;
    const _Float16* gB = B + (size_t)r0 * ldb + c0 * 8;

    char* ldsc = (char*)lds;
    char* stA = ldsc + w * 1024;              // + BUF*32768 + slot*8192
    char* stB = ldsc + 65536 + w * 1024;      // + BUF*16384 + slot*8192

    const int x0 = ((0 + lq) ^ (lr & 7)) * 16;
    const int x1 = ((4 + lq) ^ (lr & 7)) * 16;
    const char* rdA = ldsc + wm * 8192 + lr * 128;           // + BUF*32768 + mi*2048
    const char* rdB = ldsc + 65536 + wn * 8192 + lr * 128;   // + BUF*16384 + ni*2048

    half8 af[4][2], bf01[2][2], bf23[2][2];

#define STGA1(BUF, S, KOFF)                                                   \
    gload_lds16(gA + (size_t)(S) * 64 * lda + (KOFF),                         \
                stA + (BUF) * 32768 + (S) * 8192)

#define STGB1(BUF, S, KOFF)                                                   \
    gload_lds16(gB + (size_t)(S) * 64 * ldb + (KOFF),                         \
                stB + (BUF) * 16384 + (S) * 8192)

#define LDA_ALL(BUF) do {                                                     \
    const char* _p = rdA + (BUF) * 32768;                                     \
    _Pragma("unroll")                                                         \
    for (int mi = 0; mi < 4; ++mi) {                                          \
        af[mi][0] = *(const half8*)(_p + mi * 2048 + x0);                     \
        af[mi][1] = *(const half8*)(_p + mi * 2048 + x1);                     \
    }                                                                         \
} while (0)

#define LDB_H(DST, BUF, NQ) do {                                              \
    const char* _p = rdB + (BUF) * 16384 + (NQ) * 4096;                       \
    _Pragma("unroll")                                                         \
    for (int ni = 0; ni < 2; ++ni) {                                          \
        DST[ni][0] = *(const half8*)(_p + ni * 2048 + x0);                    \
        DST[ni][1] = *(const half8*)(_p + ni * 2048 + x1);                    \
    }                                                                         \
} while (0)

#define MFMA_NH(NQ, BSRC) do {                                                \
    _Pragma("unroll")                                                         \
    for (int mi = 0; mi < 4; ++mi)                                            \
    _Pragma("unroll")                                                         \
    for (int ni = 0; ni < 2; ++ni)                                            \
    _Pragma("unroll")                                                         \
    for (int kh = 0; kh < 2; ++kh) {                                          \
        if constexpr (SWAP)                                                   \
            acc[mi][(NQ)*2+ni] = __builtin_amdgcn_mfma_f32_16x16x32_f16(      \
                BSRC[ni][kh], af[mi][kh], acc[mi][(NQ)*2+ni], 0, 0, 0);       \
        else                                                                  \
            acc[mi][(NQ)*2+ni] = __builtin_amdgcn_mfma_f32_16x16x32_f16(      \
                af[mi][kh], BSRC[ni][kh], acc[mi][(NQ)*2+ni], 0, 0, 0);       \
    }                                                                         \
} while (0)

#define PH_PRE() do {                                                         \
    asm volatile("" ::: "memory");                                            \
    __builtin_amdgcn_s_barrier();                                             \
    asm volatile("s_waitcnt lgkmcnt(0)" ::: "memory");                        \
    __builtin_amdgcn_sched_barrier(0);                                        \
    __builtin_amdgcn_s_setprio(1);                                            \
} while (0)

#define PH_POST() do {                                                        \
    __builtin_amdgcn_s_setprio(0);                                            \
    __builtin_amdgcn_sched_barrier(0);                                        \
    __builtin_amdgcn_s_barrier();                                             \
    asm volatile("" ::: "memory");                                            \
} while (0)

#define KTILE(KT, BUF) do {                                                   \
    const int _k1 = ((KT) + 1) * 64, _k2 = ((KT) + 2) * 64;                   \
    const bool _s1 = (KT) + 1 < kTiles, _s2 = (KT) + 2 < kTiles;              \
    /* ph1 */                                                                 \
    LDA_ALL(BUF);                                                             \
    LDB_H(bf01, BUF, 0);                                                      \
    if (_s1) { STGB1((BUF) ^ 1, 0, _k1); STGB1((BUF) ^ 1, 1, _k1); }          \
    PH_PRE(); MFMA_NH(0, bf01); PH_POST();                                    \
    /* ph2 */                                                                 \
    LDB_H(bf23, BUF, 1);                                                      \
    if (_s2) { STGA1(BUF, 0, _k2); STGA1(BUF, 1, _k2);                        \
               STGA1(BUF, 2, _k2); STGA1(BUF, 3, _k2); }                      \
    asm volatile("" ::: "memory");                                            \
    __builtin_amdgcn_s_barrier();                                             \
    asm volatile("s_waitcnt lgkmcnt(0)" ::: "memory");                        \
    __builtin_amdgcn_sched_barrier(0);                                        \
    __builtin_amdgcn_s_setprio(1);                                            \
    MFMA_NH(1, bf23);                                                         \
    __builtin_amdgcn_s_setprio(0);                                            \
    if (_s2) asm volatile("s_waitcnt vmcnt(4)" ::: "memory");                 \
    else     asm volatile("s_waitcnt vmcnt(0)" ::: "memory");                 \
    __builtin_amdgcn_sched_barrier(0);                                        \
    __builtin_amdgcn_s_barrier();                                             \
    asm volatile("" ::: "memory");                                            \
} while (0)

    // prologue: tile0 fully (6 loads), then tile1's A (4 loads);
    // vmcnt(4) drains tile0, keeps tile1's A in flight.
    STGA1(0, 0, 0); STGA1(0, 1, 0); STGA1(0, 2, 0); STGA1(0, 3, 0);
    STGB1(0, 0, 0); STGB1(0, 1, 0);
    if (kTiles > 1) { STGA1(1, 0, 64); STGA1(1, 1, 64);
                      STGA1(1, 2, 64); STGA1(1, 3, 64); }
    if (kTiles > 1) asm volatile("s_waitcnt vmcnt(4)" ::: "memory");
    else            asm volatile("s_waitcnt vmcnt(0)" ::: "memory");
    __builtin_amdgcn_sched_barrier(0);
    __builtin_amdgcn_s_barrier();
    asm volatile("" ::: "memory");

#pragma unroll 1
    for (int kt = 0; kt < kTiles; kt += 2) {
        KTILE(kt, 0);
        KTILE(kt + 1, 1);
    }

#undef STGA1
#undef STGB1
#undef LDA_ALL
#undef LDB_H
#undef MFMA_NH
#undef PH_PRE
#undef PH_POST
#undef KTILE
}

// ---------------------------------------------------------------------------
// Merged f32->f16 conversion: x (8M elems) then Wq|Wk|Wv (3x1M) -> Wh.
// Also zeroes rsum[8192] (threads g<2048 write float4 zeros).
// ---------------------------------------------------------------------------
__global__ __launch_bounds__(256) void convert_k(
    const float* __restrict__ x, const float* __restrict__ Wq,
    const float* __restrict__ Wk, const float* __restrict__ Wv,
    _Float16* __restrict__ xh, _Float16* __restrict__ Wh,
    float* __restrict__ rsum)
{
    int g = blockIdx.x * 256 + threadIdx.x;
    if (g < 2048) {
        f32x4 z = { 0.f, 0.f, 0.f, 0.f };
        *(f32x4*)(rsum + g * 4) = z;
    }
    int i = g * 4;
    const float* src;
    _Float16* dst;
    if (i < 8388608) {                       // 4*2048*1024
        src = x + i; dst = xh + i;
    } else {
        int j = i - 8388608;                 // 0 .. 3*1048576
        int wsel = j >> 20;                  // each W is 2^20 elements
        int off  = j & 1048575;
        src = (wsel == 0 ? Wq : wsel == 1 ? Wk : Wv) + off;
        dst = Wh + j;
    }
    float4 f = *(const float4*)src;
    half4 h = { (_Float16)f.x, (_Float16)f.y, (_Float16)f.z, (_Float16)f.w };
    *(half4*)dst = h;
}

// ---------------------------------------------------------------------------
// Fused QKV on the 256x128 core: grid (32,8,3) = 768 blocks = 3.0 exact
// rounds on 256 CUs. z=0 Q[t][d], z=1 K[s][d] (SWAP, half4 along d);
// z=2 Vt[b][d][t] (non-SWAP, half4 along t).
// ---------------------------------------------------------------------------
__global__ __launch_bounds__(512, 2) void qkv_gemm256_k(
    const _Float16* __restrict__ xh, const _Float16* __restrict__ Wh,
    _Float16* __restrict__ Q, _Float16* __restrict__ K,
    _Float16* __restrict__ Vt)
{
    __shared__ __align__(16) _Float16 lds[49152];   // 96 KiB
    const int tileM = blockIdx.x * 256;
    const int tileN = blockIdx.y * 128;
    const int z     = blockIdx.z;
    const _Float16* W = Wh + (size_t)z * 1024 * 1024;

    const int lane = threadIdx.x & 63;
    const int w    = threadIdx.x >> 6;
    const int wm = w & 3, wn = w >> 2;
    const int lr = lane & 15, lq = lane >> 4;

    f32x4 acc[4][4] = {};
    if (z == 2) {
        gemm_nt_256x128<false>(xh + (size_t)tileM * 1024,
                               W + (size_t)tileN * 1024,
                               1024, 1024, 16, lds, acc);
#pragma unroll
        for (int mi = 0; mi < 4; ++mi)
#pragma unroll
            for (int ni = 0; ni < 4; ++ni) {
                int m0 = tileM + wm * 64 + mi * 16 + lq * 4;
                int n  = tileN + wn * 64 + ni * 16 + lr;
                int b = m0 >> 11, tt = m0 & 2047;
                half4 h = { (_Float16)acc[mi][ni][0], (_Float16)acc[mi][ni][1],
                            (_Float16)acc[mi][ni][2], (_Float16)acc[mi][ni][3] };
                *(half4*)(Vt + (size_t)b * 2048 * 1024 + (size_t)n * 2048 + tt) = h;
            }
    } else {
        gemm_nt_256x128<true>(xh + (size_t)tileM * 1024,
                              W + (size_t)tileN * 1024,
                              1024, 1024, 16, lds, acc);
        _Float16* O = (z == 0) ? Q : K;
#pragma unroll
        for (int mi = 0; mi < 4; ++mi)
#pragma unroll
            for (int ni = 0; ni < 4; ++ni) {
                int tt = tileM + wm * 64 + mi * 16 + lr;
                int d0 = tileN + wn * 64 + ni * 16 + lq * 4;
                half4 h = { (_Float16)acc[mi][ni][0], (_Float16)acc[mi][ni][1],
                            (_Float16)acc[mi][ni][2], (_Float16)acc[mi][ni][3] };
                *(half4*)(O + (size_t)tt * 1024 + d0) = h;
            }
    }
}

// ---------------------------------------------------------------------------
// Scores: DENSE triangular grid, 544 blocks, 1-D launch, XCD chunk swizzle
// (544=68x8). Writes E = exp(x*scale - 6) (masked -> 0; constant-shift
// softmax, verified R12-R18) + atomic row-sums into rsum.
// R19: LDS-staged COALESCED store. Old epilogue wrote half4 with lanes on
// rows 4KB apart -> 32B partial-line fragments -> WRITE_SIZE 77 MB vs 18
// ideal (4.3x, R17 counters). Now: exp-applied tile -> LDS [128][136]
// (pad 136 halves = 272B rows: 16B-aligned, bank offset 4 -> <=2-way
// alias = free per m136), then copy out with each instruction covering
// 4 full rows x 256B contiguous. LDS 34816B (still 4 blocks/CU).
// ---------------------------------------------------------------------------
__global__ __launch_bounds__(256) void scores_gemm_k(
    const _Float16* __restrict__ Q, const _Float16* __restrict__ K,
    _Float16* __restrict__ S, float* __restrict__ rsum)
{
    // triangular decode
    const int bid = blockIdx.x;
    const int n   = (bid & 7) * 68 + (bid >> 3);   // bijective swizzle
    const int b   = n / 136;
    const int m   = n - b * 136;
    int ti = (int)((sqrtf(8.f * (float)m + 1.f) - 1.f) * 0.5f);
    while ((ti + 1) * (ti + 2) / 2 <= m) ++ti;     // fixup (float safety)
    while (ti * (ti + 1) / 2 > m) --ti;
    const int si = m - ti * (ti + 1) / 2;
    const int tileT = ti * 128, tileS = si * 128;

    // 34816 B: core uses first 16384 halves (A 8192 | B 8192); epilogue
    // reuses the whole thing as a 128 x 136-padded fp16 tile.
    __shared__ __align__(16) _Float16 lds[17408];
    _Float16* ldsA = lds;
    _Float16* ldsB = lds + 8192;

    f32x4 acc[4][4] = {};
    gemm_nt_core<128, 128, 2, 2, true>(
        Q + (size_t)b * 2048 * 1024 + (size_t)tileT * 1024,
        K + (size_t)b * 2048 * 1024 + (size_t)tileS * 1024,
        1024, 1024, 0, 1024, ldsA, ldsB, acc);

    const int lane = threadIdx.x & 63;
    const int w    = threadIdx.x >> 6;
    const int wm = w & 1, wn = w >> 1;
    const int lr = lane & 15, lq = lane >> 4;
    const float scale = 0.03125f;  // 1024^-0.5

    __syncthreads();   // core's last LDS reads done before tile reuse

    float rp[4] = { 0.f, 0.f, 0.f, 0.f };
#pragma unroll
    for (int mi = 0; mi < 4; ++mi)
#pragma unroll
        for (int ni = 0; ni < 4; ++ni) {
            int rloc = wm * 64 + mi * 16 + lr;       // tile-local row
            int tt   = tileT + rloc;
            int s0   = tileS + wn * 64 + ni * 16 + lq * 4;
            half4 h;
#pragma unroll
            for (int r = 0; r < 4; ++r) {
                float e = __expf(fmaf(acc[mi][ni][r], scale, -6.0f));
                h[r] = (s0 + r <= tt) ? (_Float16)e : (_Float16)0.f;
                rp[mi] += (float)h[r];
            }
            *(half4*)(lds + (size_t)rloc * 136 + (wn * 64 + ni * 16 + lq * 4)) = h;
        }

    // fold the 4 lq-lanes holding the same row (lane bits 4,5)
#pragma unroll
    for (int mi = 0; mi < 4; ++mi) {
        rp[mi] += __shfl_xor(rp[mi], 16);
        rp[mi] += __shfl_xor(rp[mi], 32);
    }
    if (lq == 0) {
#pragma unroll
        for (int mi = 0; mi < 4; ++mi) {
            int tt = tileT + wm * 64 + mi * 16 + lr;
            atomicAdd(&rsum[(size_t)b * 2048 + tt], rp[mi]);
        }
    }

    __syncthreads();   // staged tile visible

    // coalesced copy-out: 2048 half8 chunks; per instruction a wave covers
    // 4 consecutive rows x 16 chunks = 4 x 256B contiguous segments.
#pragma unroll
    for (int i = 0; i < 8; ++i) {
        int c   = threadIdx.x + 256 * i;
        int row = c >> 4, ch = c & 15;
        half8 v = *(const half8*)(lds + (size_t)row * 136 + ch * 8);
        *(half8*)(S + ((size_t)b * 2048 + tileT + row) * 2048 + tileS + ch * 8) = v;
    }
}

// ---------------------------------------------------------------------------
// PV: 128(t) x 128(d) tiles, 1-D grid 512 with bijective XCD chunk swizzle
// (512=64x8): n=(bid&7)*64 + bid>>3 -> XCD k owns 4 complete (b,d)
// Vt-panel groups (16 t-blocks each, t fastest so the 16 blocks sharing a
// Vt panel are contiguous on ONE XCD; 4 panels = 2 MB < 4 MB L2).
// Longest-t first within groups. Default launch bounds (no VGPR clamp).
// A = E (unnorm exp), epilogue divides by rsum[t].
// ---------------------------------------------------------------------------
__global__ __launch_bounds__(256) void pv_gemm_k(
    const _Float16* __restrict__ P, const _Float16* __restrict__ Vt,
    const float* __restrict__ rsum, float* __restrict__ out)
{
    __shared__ __align__(16) _Float16 ldsA[128 * 64];
    __shared__ __align__(16) _Float16 ldsB[128 * 64];
    const int bid = blockIdx.x;
    const int n   = (bid & 7) * 64 + (bid >> 3);   // XCD chunk swizzle
    const int tio = n & 15;
    const int d   = (n >> 4) & 7;
    const int b   = n >> 7;
    const int tileT = (15 - tio) * 128;            // longest-first
    const int tileD = d * 128;
    const int kEnd  = tileT + 128;

    f32x4 acc[4][4] = {};
    gemm_nt_core<128, 128, 2, 2, true>(
        P + ((size_t)b * 2048 + tileT) * 2048,
        Vt + (size_t)b * 1024 * 2048 + (size_t)tileD * 2048,
        2048, 2048, 0, kEnd, ldsA, ldsB, acc);

    const int lane = threadIdx.x & 63;
    const int w    = threadIdx.x >> 6;
    const int wm = w & 1, wn = w >> 1;
    const int lr = lane & 15, lq = lane >> 4;

#pragma unroll
    for (int mi = 0; mi < 4; ++mi) {
        const int tt = tileT + wm * 64 + mi * 16 + lr;
        const float inv = 1.0f / rsum[(size_t)b * 2048 + tt];
#pragma unroll
        for (int ni = 0; ni < 4; ++ni) {
            int d0 = tileD + wn * 64 + ni * 16 + lq * 4;
            f32x4 o = { acc[mi][ni][0] * inv, acc[mi][ni][1] * inv,
                        acc[mi][ni][2] * inv, acc[mi][ni][3] * inv };
            *(f32x4*)(out + ((size_t)b * 2048 + tt) * 1024 + d0) = o;
        }
    }
}

// ---------------------------------------------------------------------------
extern "C" void kernel_launch(void* const* d_in, const int* in_sizes, int n_in,
                              void* d_out, int out_size, void* d_ws, size_t ws_size,
                              hipStream_t stream)
{
    const float* x  = (const float*)d_in[0];
    const float* Wq = (const float*)d_in[1];
    const float* Wk = (const float*)d_in[2];
    const float* Wv = (const float*)d_in[3];
    float* out = (float*)d_out;

    char* ws = (char*)d_ws;
    // layout (MB): xh 0..16 | Wh 16..22 | Q 22..38 | K 38..54 | Vt 54..70 |
    // S16 70..102 | rsum 102..102.03.  Total ~102.1 MB.
    _Float16* xh = (_Float16*)(ws);
    _Float16* Wh = (_Float16*)(ws + (16u << 20));
    _Float16* Qh = (_Float16*)(ws + (22u << 20));
    _Float16* Kh = (_Float16*)(ws + (38u << 20));
    _Float16* Vt = (_Float16*)(ws + (54u << 20));
    _Float16* S  = (_Float16*)(ws + (70u << 20));
    float*    rs = (float*)   (ws + (102u << 20));

    convert_k<<<11264, 256, 0, stream>>>(x, Wq, Wk, Wv, xh, Wh, rs);

    qkv_gemm256_k<<<dim3(32, 8, 3), 512, 0, stream>>>(xh, Wh, Qh, Kh, Vt);

    scores_gemm_k<<<544, 256, 0, stream>>>(Qh, Kh, S, rs);
    pv_gemm_k<<<512, 256, 0, stream>>>(S, Vt, rs, out);
}